// Round 13
// baseline (62.838 us; speedup 1.0000x reference)
//
#include <hip/hip_runtime.h>

#define N_QUBITS 5
#define DIM 32

// ---------- verified perm machinery (rounds 1/2/7-12) ----------
__host__ __device__ constexpr int cnot_apply(int i, int ctrl, int tgt) {
    const int pc = N_QUBITS - 1 - ctrl;
    const int pt = N_QUBITS - 1 - tgt;
    return i ^ (((i >> pc) & 1) << pt);
}
__host__ __device__ constexpr int layer_perm(int i, int r) {
    int idx = i;
    for (int q = N_QUBITS - 1; q >= 0; --q)
        idx = cnot_apply(idx, q, (q + r) % N_QUBITS);
    return idx;
}

// Scalar SoA, 1 batch/thread: 262144 threads -> 4096 waves -> 4 waves/SIMD.
// Same total work as round 10 (pk ops are FLOP-neutral on CDNA), double the TLP.
__global__ __launch_bounds__(256, 4) void vqc_kernel(
    const float* __restrict__ x,      // (B, 5)
    const float* __restrict__ w,      // (2, 5, 3)
    const float* __restrict__ fc_w,   // (8, 5)
    const float* __restrict__ fc_b,   // (8,)
    float* __restrict__ out,          // (B, 8)
    int Btot)
{
    // ---- block-uniform gate precompute (round-10 verbatim preamble) ----
    __shared__ float s_g0[N_QUBITS][8];   // layer 0: 8 raw coeffs
    __shared__ float s_g1[N_QUBITS][4];   // layer 1: c00r,c00i,c01r,c01i
    __shared__ float s_fc_w[40];
    __shared__ float s_fc_b[8];

    const int t = threadIdx.x;
    if (t < 2 * N_QUBITS) {
        const float phi = w[t * 3 + 0];
        const float th  = w[t * 3 + 1];
        const float om  = w[t * 3 + 2];
        float s, c;   sincosf(0.5f * th, &s, &c);
        float sp, cp; sincosf(0.5f * (phi + om), &sp, &cp);
        float sm, cm; sincosf(0.5f * (phi - om), &sm, &cm);
        const float g00r =  cp * c, g00i = -sp * c;
        const float g01r = -cm * s, g01i = -sm * s;
        const float g10r =  cm * s, g10i = -sm * s;
        const float g11r =  cp * c, g11i =  sp * c;
        if (t < N_QUBITS) {
            s_g0[t][0] = g00r; s_g0[t][1] = g00i;
            s_g0[t][2] = g01r; s_g0[t][3] = g01i;
            s_g0[t][4] = g10r; s_g0[t][5] = g10i;
            s_g0[t][6] = g11r; s_g0[t][7] = g11i;
        } else {
            const int q = t - N_QUBITS;
            s_g1[q][0] = g00r; s_g1[q][1] = g00i;
            s_g1[q][2] = g01r; s_g1[q][3] = g01i;
        }
    } else if (t >= 16 && t < 56) {
        s_fc_w[t - 16] = fc_w[t - 16];
    } else if (t >= 56 && t < 64) {
        s_fc_b[t - 56] = fc_b[t - 56];
    }
    __syncthreads();

    const int b = blockIdx.x * 256 + t;
    if (b >= Btot) return;

    const float* xp = x + (size_t)b * 5;

    // ---- build: post-layer-0 product state (round-9/10 v-formulas, scalar) ----
    float sre[DIM], sim[DIM];
    {
        float s, c;
        __sincosf(0.5f * xp[0], &s, &c);
        sre[0]  = s_g0[0][0] * c + s_g0[0][3] * s;
        sim[0]  = s_g0[0][1] * c - s_g0[0][2] * s;
        sre[16] = s_g0[0][4] * c + s_g0[0][7] * s;
        sim[16] = s_g0[0][5] * c - s_g0[0][6] * s;
    }
#pragma unroll
    for (int q = 1; q < N_QUBITS; ++q) {
        float s, c;
        __sincosf(0.5f * xp[q], &s, &c);
        const float v0re = s_g0[q][0] * c + s_g0[q][3] * s;
        const float v0im = s_g0[q][1] * c - s_g0[q][2] * s;
        const float v1re = s_g0[q][4] * c + s_g0[q][7] * s;
        const float v1im = s_g0[q][5] * c - s_g0[q][6] * s;
        const int stride = 1 << (4 - q);
#pragma unroll
        for (int k = 0; k < (1 << q); ++k) {
            const int m = k * (stride << 1);
            const float are = sre[m], aim = sim[m];
            sre[m + stride] = v1re * are - v1im * aim;
            sim[m + stride] = v1re * aim + v1im * are;
            sre[m]          = v0re * are - v0im * aim;
            sim[m]          = v0re * aim + v0im * are;
        }
    }

    // ---- layer 1: 5 Rot butterflies on pi1-composed indices (round-8 formulas) ----
#pragma unroll
    for (int q = 0; q < N_QUBITS; ++q) {
        const float c00r = s_g1[q][0], c00i = s_g1[q][1];
        const float c01r = s_g1[q][2], c01i = s_g1[q][3];
        const int stride = 1 << (4 - q);
        const int mask = stride - 1;
#pragma unroll
        for (int p = 0; p < DIM / 2; ++p) {
            const int a0 = ((p & ~mask) << 1) | (p & mask);
            const int ia = layer_perm(a0, 1);
            const int ib = layer_perm(a0 + stride, 1);
            const float ar = sre[ia], ai = sim[ia];
            const float br = sre[ib], bi = sim[ib];
            sre[ia] =  c00r * ar - c00i * ai + c01r * br - c01i * bi;
            sim[ia] =  c00r * ai + c00i * ar + c01r * bi + c01i * br;
            sre[ib] = -c01r * ar - c01i * ai + c00r * br + c00i * bi;
            sim[ib] = -c01r * ai + c01i * ar - c00i * br + c00r * bi;
        }
    }

    // ---- probs, both perms folded: final[i] = st[pi1(pi2(i))] (round-9/10) ----
    float pr[DIM];
#pragma unroll
    for (int i = 0; i < DIM; ++i) {
        const int j = layer_perm(layer_perm(i, 2), 1);
        pr[i] = sre[j] * sre[j] + sim[j] * sim[j];
    }

    // ---- expvals via Walsh-Hadamard partial-sum tree (round-2 verbatim) ----
    float v16[16], v8_[8], v4_[4], v2_[2];
    float ev4 = 0.f, ev3 = 0.f, ev2 = 0.f, ev1 = 0.f, ev0;
#pragma unroll
    for (int j = 0; j < 16; ++j) { v16[j] = pr[2*j] + pr[2*j+1]; ev4 += pr[2*j] - pr[2*j+1]; }
#pragma unroll
    for (int j = 0; j < 8; ++j)  { v8_[j] = v16[2*j] + v16[2*j+1]; ev3 += v16[2*j] - v16[2*j+1]; }
#pragma unroll
    for (int j = 0; j < 4; ++j)  { v4_[j] = v8_[2*j] + v8_[2*j+1]; ev2 += v8_[2*j] - v8_[2*j+1]; }
#pragma unroll
    for (int j = 0; j < 2; ++j)  { v2_[j] = v4_[2*j] + v4_[2*j+1]; ev1 += v4_[2*j] - v4_[2*j+1]; }
    ev0 = v2_[0] - v2_[1];
    const float ev[N_QUBITS] = {ev0, ev1, ev2, ev3, ev4};

    // ---- FC: out[b,j] = sum_q ev[q]*fc_w[j,q] + fc_b[j] ----
    float o[8];
#pragma unroll
    for (int j = 0; j < 8; ++j) {
        float acc = s_fc_b[j];
#pragma unroll
        for (int q = 0; q < 5; ++q) acc += ev[q] * s_fc_w[j * 5 + q];
        o[j] = acc;
    }
    float4* op = (float4*)(out + (size_t)b * 8);
    op[0] = make_float4(o[0], o[1], o[2], o[3]);
    op[1] = make_float4(o[4], o[5], o[6], o[7]);
}

extern "C" void kernel_launch(void* const* d_in, const int* in_sizes, int n_in,
                              void* d_out, int out_size, void* d_ws, size_t ws_size,
                              hipStream_t stream) {
    const float* x    = (const float*)d_in[0];
    const float* w    = (const float*)d_in[1];
    const float* fc_w = (const float*)d_in[2];
    const float* fc_b = (const float*)d_in[3];
    float* out = (float*)d_out;

    const int Btot = in_sizes[0] / N_QUBITS;   // 262144
    const int grid = (Btot + 255) / 256;       // 1024 blocks, 4096 waves, 4/SIMD
    hipLaunchKernelGGL(vqc_kernel, dim3(grid), dim3(256), 0, stream,
                       x, w, fc_w, fc_b, out, Btot);
}

// Round 14
// 20.703 us; speedup vs baseline: 3.0352x; 3.0352x over previous
//
#include <hip/hip_runtime.h>

#define N_QUBITS 5
#define DIM 32

// ---------- verified perm machinery (rounds 1/2/7-13) ----------
__host__ __device__ constexpr int cnot_apply(int i, int ctrl, int tgt) {
    const int pc = N_QUBITS - 1 - ctrl;
    const int pt = N_QUBITS - 1 - tgt;
    return i ^ (((i >> pc) & 1) << pt);
}
__host__ __device__ constexpr int layer_perm(int i, int r) {
    int idx = i;
    for (int q = N_QUBITS - 1; q >= 0; --q)
        idx = cnot_apply(idx, q, (q + r) % N_QUBITS);
    return idx;
}
__host__ __device__ constexpr int invP1(int p) {   // inverse of layer_perm(.,1)
    for (int l = 0; l < 32; ++l) if (layer_perm(l, 1) == p) return l;
    return 0;
}

// Scalar, 1 batch/thread, RZ-factored layer 1:
//   Rot(phi,th,om) = RZ(om)·RY(th)·RZ(phi)  [verified vs reference g-matrix]
//   layer-1 RZ(om): killed by |.|^2  -> dropped
//   layer-1 RZ(phi) x5: one 32-phase diagonal ph[j], applied to st[j] via invP1
//   layer-1 RY: real butterflies, 8 FMA/pair
__global__ __launch_bounds__(256, 3) void vqc_kernel(
    const float* __restrict__ x,      // (B, 5)
    const float* __restrict__ w,      // (2, 5, 3)
    const float* __restrict__ fc_w,   // (8, 5)
    const float* __restrict__ fc_b,   // (8,)
    float* __restrict__ out,          // (B, 8)
    int Btot)
{
    __shared__ float s_g0[N_QUBITS][8];   // layer 0: full Rot coeffs (folded w/ RX)
    __shared__ float s_cs[N_QUBITS][2];   // layer 1: (cos(th/2), sin(th/2))
    __shared__ float s_phr[DIM];          // layer-1 phi-diagonal, re
    __shared__ float s_phi[DIM];          // layer-1 phi-diagonal, im
    __shared__ float s_fc_w[40];
    __shared__ float s_fc_b[8];

    const int t = threadIdx.x;
    if (t < N_QUBITS) {                   // layer-0 gates: full matrix
        const float phi = w[t * 3 + 0];
        const float th  = w[t * 3 + 1];
        const float om  = w[t * 3 + 2];
        float s, c;   sincosf(0.5f * th, &s, &c);
        float sp, cp; sincosf(0.5f * (phi + om), &sp, &cp);
        float sm, cm; sincosf(0.5f * (phi - om), &sm, &cm);
        s_g0[t][0] =  cp * c;  s_g0[t][1] = -sp * c;   // g00
        s_g0[t][2] = -cm * s;  s_g0[t][3] = -sm * s;   // g01
        s_g0[t][4] =  cm * s;  s_g0[t][5] = -sm * s;   // g10
        s_g0[t][6] =  cp * c;  s_g0[t][7] =  sp * c;   // g11
    } else if (t >= 8 && t < 13) {        // layer-1 RY coeffs
        const int q = t - 8;
        float s, c;
        sincosf(0.5f * w[(N_QUBITS + q) * 3 + 1], &s, &c);
        s_cs[q][0] = c;  s_cs[q][1] = s;
    } else if (t >= 32 && t < 64) {       // layer-1 phi-diagonal (32 phases)
        const int j = t - 32;
        const int i = invP1(j);           // runtime use of verified constexpr, preamble-only
        float ang = 0.f;
#pragma unroll
        for (int q = 0; q < N_QUBITS; ++q) {
            const float ph = w[(N_QUBITS + q) * 3 + 0];
            ang += ((i >> (4 - q)) & 1) ? 0.5f * ph : -0.5f * ph;
        }
        float s, c;
        sincosf(ang, &s, &c);
        s_phr[j] = c;  s_phi[j] = s;
    } else if (t >= 64 && t < 104) {
        s_fc_w[t - 64] = fc_w[t - 64];
    } else if (t >= 104 && t < 112) {
        s_fc_b[t - 104] = fc_b[t - 104];
    }
    __syncthreads();

    const int b = blockIdx.x * 256 + t;
    if (b >= Btot) return;

    const float* xp = x + (size_t)b * 5;

    // ---- build: post-layer-0 product state (r13-verified scalar code) ----
    float sre[DIM], sim[DIM];
    {
        float s, c;
        __sincosf(0.5f * xp[0], &s, &c);
        sre[0]  = s_g0[0][0] * c + s_g0[0][3] * s;
        sim[0]  = s_g0[0][1] * c - s_g0[0][2] * s;
        sre[16] = s_g0[0][4] * c + s_g0[0][7] * s;
        sim[16] = s_g0[0][5] * c - s_g0[0][6] * s;
    }
#pragma unroll
    for (int q = 1; q < N_QUBITS; ++q) {
        float s, c;
        __sincosf(0.5f * xp[q], &s, &c);
        const float v0re = s_g0[q][0] * c + s_g0[q][3] * s;
        const float v0im = s_g0[q][1] * c - s_g0[q][2] * s;
        const float v1re = s_g0[q][4] * c + s_g0[q][7] * s;
        const float v1im = s_g0[q][5] * c - s_g0[q][6] * s;
        const int stride = 1 << (4 - q);
#pragma unroll
        for (int k = 0; k < (1 << q); ++k) {
            const int m = k * (stride << 1);
            const float are = sre[m], aim = sim[m];
            sre[m + stride] = v1re * are - v1im * aim;
            sim[m + stride] = v1re * aim + v1im * are;
            sre[m]          = v0re * are - v0im * aim;
            sim[m]          = v0re * aim + v0im * are;
        }
    }

    // ---- layer-1 phi-diagonal: st[j] *= ph[j] ----
#pragma unroll
    for (int j = 0; j < DIM; ++j) {
        const float pr_ = s_phr[j], pi_ = s_phi[j];
        const float re = sre[j], im = sim[j];
        sre[j] = re * pr_ - im * pi_;
        sim[j] = re * pi_ + im * pr_;
    }

    // ---- layer 1: 5 real RY butterflies on pi1-composed indices ----
    // pair enumeration r13-verified; RY: a' = c*a - s*b ; b' = s*a + c*b
#pragma unroll
    for (int q = 0; q < N_QUBITS; ++q) {
        const float c = s_cs[q][0], s = s_cs[q][1];
        const int stride = 1 << (4 - q);
        const int mask = stride - 1;
#pragma unroll
        for (int p = 0; p < DIM / 2; ++p) {
            const int a0 = ((p & ~mask) << 1) | (p & mask);
            const int ia = layer_perm(a0, 1);
            const int ib = layer_perm(a0 + stride, 1);
            const float ar = sre[ia], ai = sim[ia];
            const float br = sre[ib], bi = sim[ib];
            sre[ia] = c * ar - s * br;
            sim[ia] = c * ai - s * bi;
            sre[ib] = s * ar + c * br;
            sim[ib] = s * ai + c * bi;
        }
    }

    // ---- probs, both perms folded (r13 verbatim) ----
    float pr[DIM];
#pragma unroll
    for (int i = 0; i < DIM; ++i) {
        const int j = layer_perm(layer_perm(i, 2), 1);
        pr[i] = sre[j] * sre[j] + sim[j] * sim[j];
    }

    // ---- expvals via Walsh-Hadamard partial-sum tree (r13 verbatim) ----
    float v16[16], v8_[8], v4_[4], v2_[2];
    float ev4 = 0.f, ev3 = 0.f, ev2 = 0.f, ev1 = 0.f, ev0;
#pragma unroll
    for (int j = 0; j < 16; ++j) { v16[j] = pr[2*j] + pr[2*j+1]; ev4 += pr[2*j] - pr[2*j+1]; }
#pragma unroll
    for (int j = 0; j < 8; ++j)  { v8_[j] = v16[2*j] + v16[2*j+1]; ev3 += v16[2*j] - v16[2*j+1]; }
#pragma unroll
    for (int j = 0; j < 4; ++j)  { v4_[j] = v8_[2*j] + v8_[2*j+1]; ev2 += v8_[2*j] - v8_[2*j+1]; }
#pragma unroll
    for (int j = 0; j < 2; ++j)  { v2_[j] = v4_[2*j] + v4_[2*j+1]; ev1 += v4_[2*j] - v4_[2*j+1]; }
    ev0 = v2_[0] - v2_[1];
    const float ev[N_QUBITS] = {ev0, ev1, ev2, ev3, ev4};

    // ---- FC + coalesced store (r13 verbatim) ----
    float o[8];
#pragma unroll
    for (int j = 0; j < 8; ++j) {
        float acc = s_fc_b[j];
#pragma unroll
        for (int q = 0; q < 5; ++q) acc += ev[q] * s_fc_w[j * 5 + q];
        o[j] = acc;
    }
    float4* op = (float4*)(out + (size_t)b * 8);
    op[0] = make_float4(o[0], o[1], o[2], o[3]);
    op[1] = make_float4(o[4], o[5], o[6], o[7]);
}

extern "C" void kernel_launch(void* const* d_in, const int* in_sizes, int n_in,
                              void* d_out, int out_size, void* d_ws, size_t ws_size,
                              hipStream_t stream) {
    const float* x    = (const float*)d_in[0];
    const float* w    = (const float*)d_in[1];
    const float* fc_w = (const float*)d_in[2];
    const float* fc_b = (const float*)d_in[3];
    float* out = (float*)d_out;

    const int Btot = in_sizes[0] / N_QUBITS;   // 262144
    const int grid = (Btot + 255) / 256;       // 1024 blocks
    hipLaunchKernelGGL(vqc_kernel, dim3(grid), dim3(256), 0, stream,
                       x, w, fc_w, fc_b, out, Btot);
}

// Round 15
// 14.913 us; speedup vs baseline: 4.2136x; 1.3882x over previous
//
#include <hip/hip_runtime.h>

typedef float f2 __attribute__((ext_vector_type(2)));

#define N_QUBITS 5
#define DIM 32

// ---------- verified perm machinery (rounds 1/2/7-14) ----------
__host__ __device__ constexpr int cnot_apply(int i, int ctrl, int tgt) {
    const int pc = N_QUBITS - 1 - ctrl;
    const int pt = N_QUBITS - 1 - tgt;
    return i ^ (((i >> pc) & 1) << pt);
}
__host__ __device__ constexpr int layer_perm(int i, int r) {
    int idx = i;
    for (int q = N_QUBITS - 1; q >= 0; --q)
        idx = cnot_apply(idx, q, (q + r) % N_QUBITS);
    return idx;
}
__host__ __device__ constexpr int invP1(int p) {   // inverse of layer_perm(.,1)
    for (int l = 0; l < 32; ++l) if (layer_perm(l, 1) == p) return l;
    return 0;
}

// r10 packed-f2 2-batch structure  +  r14 RZ-factored layer 1:
//   Rot(phi,th,om) = RZ(om)·RY(th)·RZ(phi)   [r14 PASS-verified]
//   layer-1 RZ(om): killed by |.|^2 -> dropped
//   layer-1 RZ(phi) x5: one 32-phase diagonal (block-uniform, LDS)
//   layer-1 RY: real butterflies (8 pk ops/pair instead of 16)
__global__ __launch_bounds__(256, 2) void vqc_kernel(
    const float* __restrict__ x,      // (B, 5)
    const float* __restrict__ w,      // (2, 5, 3)
    const float* __restrict__ fc_w,   // (8, 5)
    const float* __restrict__ fc_b,   // (8,)
    float* __restrict__ out,          // (B, 8)
    int Btot)
{
    // ---- block-uniform precompute (r14-verified preamble) ----
    __shared__ float s_g0[N_QUBITS][8];   // layer 0: full Rot coeffs
    __shared__ float s_cs[N_QUBITS][2];   // layer 1: (cos(th/2), sin(th/2))
    __shared__ float s_phr[DIM];          // layer-1 phi-diagonal, re
    __shared__ float s_phi[DIM];          // layer-1 phi-diagonal, im
    __shared__ float s_fc_w[40];
    __shared__ float s_fc_b[8];

    const int t = threadIdx.x;
    if (t < N_QUBITS) {                   // layer-0 gates: full matrix
        const float phi = w[t * 3 + 0];
        const float th  = w[t * 3 + 1];
        const float om  = w[t * 3 + 2];
        float s, c;   sincosf(0.5f * th, &s, &c);
        float sp, cp; sincosf(0.5f * (phi + om), &sp, &cp);
        float sm, cm; sincosf(0.5f * (phi - om), &sm, &cm);
        s_g0[t][0] =  cp * c;  s_g0[t][1] = -sp * c;   // g00
        s_g0[t][2] = -cm * s;  s_g0[t][3] = -sm * s;   // g01
        s_g0[t][4] =  cm * s;  s_g0[t][5] = -sm * s;   // g10
        s_g0[t][6] =  cp * c;  s_g0[t][7] =  sp * c;   // g11
    } else if (t >= 8 && t < 13) {        // layer-1 RY coeffs
        const int q = t - 8;
        float s, c;
        sincosf(0.5f * w[(N_QUBITS + q) * 3 + 1], &s, &c);
        s_cs[q][0] = c;  s_cs[q][1] = s;
    } else if (t >= 32 && t < 64) {       // layer-1 phi-diagonal (32 phases)
        const int j = t - 32;
        const int i = invP1(j);
        float ang = 0.f;
#pragma unroll
        for (int q = 0; q < N_QUBITS; ++q) {
            const float ph = w[(N_QUBITS + q) * 3 + 0];
            ang += ((i >> (4 - q)) & 1) ? 0.5f * ph : -0.5f * ph;
        }
        float s, c;
        sincosf(ang, &s, &c);
        s_phr[j] = c;  s_phi[j] = s;
    } else if (t >= 64 && t < 104) {
        s_fc_w[t - 64] = fc_w[t - 64];
    } else if (t >= 104 && t < 112) {
        s_fc_b[t - 104] = fc_b[t - 104];
    }
    __syncthreads();

    const int b0 = blockIdx.x * 512 + t;
    if (b0 >= Btot) return;
    const int b1 = b0 + 256;
    const int b1c = (b1 < Btot) ? b1 : b0;        // clamp for loads only

    const float* xp0 = x + (size_t)b0 * 5;
    const float* xp1 = x + (size_t)b1c * 5;

    // ---- build: post-layer-0 product state (r10 verbatim, packed f2 SoA) ----
    f2 sre[DIM], sim[DIM];
    {
        float s0, c0, s1, c1;
        __sincosf(0.5f * xp0[0], &s0, &c0);
        __sincosf(0.5f * xp1[0], &s1, &c1);
        const f2 cc = f2{c0, c1}, ss = f2{s0, s1};
        sre[0]  = s_g0[0][0] * cc + s_g0[0][3] * ss;
        sim[0]  = s_g0[0][1] * cc - s_g0[0][2] * ss;
        sre[16] = s_g0[0][4] * cc + s_g0[0][7] * ss;
        sim[16] = s_g0[0][5] * cc - s_g0[0][6] * ss;
    }
#pragma unroll
    for (int q = 1; q < N_QUBITS; ++q) {
        float s0, c0, s1, c1;
        __sincosf(0.5f * xp0[q], &s0, &c0);
        __sincosf(0.5f * xp1[q], &s1, &c1);
        const f2 cc = f2{c0, c1}, ss = f2{s0, s1};
        const f2 v0re = s_g0[q][0] * cc + s_g0[q][3] * ss;
        const f2 v0im = s_g0[q][1] * cc - s_g0[q][2] * ss;
        const f2 v1re = s_g0[q][4] * cc + s_g0[q][7] * ss;
        const f2 v1im = s_g0[q][5] * cc - s_g0[q][6] * ss;
        const int stride = 1 << (4 - q);
#pragma unroll
        for (int k = 0; k < (1 << q); ++k) {
            const int m = k * (stride << 1);
            const f2 are = sre[m], aim = sim[m];
            sre[m + stride] = v1re * are - v1im * aim;
            sim[m + stride] = v1re * aim + v1im * are;
            sre[m]          = v0re * are - v0im * aim;
            sim[m]          = v0re * aim + v0im * are;
        }
    }

    // ---- layer-1 phi-diagonal: st[j] *= ph[j]  (r14 algebra, packed) ----
#pragma unroll
    for (int j = 0; j < DIM; ++j) {
        const float pr_ = s_phr[j], pi_ = s_phi[j];
        const f2 re = sre[j], im = sim[j];
        sre[j] = re * pr_ - im * pi_;
        sim[j] = re * pi_ + im * pr_;
    }

    // ---- layer 1: 5 real RY butterflies on pi1-composed indices (r14, packed) ----
#pragma unroll
    for (int q = 0; q < N_QUBITS; ++q) {
        const float c = s_cs[q][0], s = s_cs[q][1];
        const int stride = 1 << (4 - q);
        const int mask = stride - 1;
#pragma unroll
        for (int p = 0; p < DIM / 2; ++p) {
            const int a0 = ((p & ~mask) << 1) | (p & mask);
            const int ia = layer_perm(a0, 1);
            const int ib = layer_perm(a0 + stride, 1);
            const f2 ar = sre[ia], ai = sim[ia];
            const f2 br = sre[ib], bi = sim[ib];
            sre[ia] = c * ar - s * br;
            sim[ia] = c * ai - s * bi;
            sre[ib] = s * ar + c * br;
            sim[ib] = s * ai + c * bi;
        }
    }

    // ---- probs, both perms folded (r10 verbatim) ----
    f2 pr[DIM];
#pragma unroll
    for (int i = 0; i < DIM; ++i) {
        const int j = layer_perm(layer_perm(i, 2), 1);
        pr[i] = sre[j] * sre[j] + sim[j] * sim[j];
    }

    // ---- expvals via Walsh-Hadamard partial-sum tree (r10 verbatim, packed) ----
    f2 v16[16], v8_[8], v4_[4], v2_[2];
    f2 ev4 = f2{0.f, 0.f}, ev3 = f2{0.f, 0.f}, ev2 = f2{0.f, 0.f}, ev1 = f2{0.f, 0.f};
#pragma unroll
    for (int j = 0; j < 16; ++j) { v16[j] = pr[2*j] + pr[2*j+1]; ev4 += pr[2*j] - pr[2*j+1]; }
#pragma unroll
    for (int j = 0; j < 8; ++j)  { v8_[j] = v16[2*j] + v16[2*j+1]; ev3 += v16[2*j] - v16[2*j+1]; }
#pragma unroll
    for (int j = 0; j < 4; ++j)  { v4_[j] = v8_[2*j] + v8_[2*j+1]; ev2 += v8_[2*j] - v8_[2*j+1]; }
#pragma unroll
    for (int j = 0; j < 2; ++j)  { v2_[j] = v4_[2*j] + v4_[2*j+1]; ev1 += v4_[2*j] - v4_[2*j+1]; }
    const f2 ev0 = v2_[0] - v2_[1];
    const f2 ev[N_QUBITS] = {ev0, ev1, ev2, ev3, ev4};

    // ---- FC (packed over both batches, r10 verbatim) ----
    f2 o[8];
#pragma unroll
    for (int j = 0; j < 8; ++j) {
        f2 acc = f2{s_fc_b[j], s_fc_b[j]};
#pragma unroll
        for (int q = 0; q < 5; ++q) acc += ev[q] * s_fc_w[j * 5 + q];
        o[j] = acc;
    }

    // ---- stores: two coalesced float4 pairs (r10 verbatim) ----
    float4* op0 = (float4*)(out + (size_t)b0 * 8);
    op0[0] = make_float4(o[0].x, o[1].x, o[2].x, o[3].x);
    op0[1] = make_float4(o[4].x, o[5].x, o[6].x, o[7].x);
    if (b1 < Btot) {
        float4* op1 = (float4*)(out + (size_t)b1 * 8);
        op1[0] = make_float4(o[0].y, o[1].y, o[2].y, o[3].y);
        op1[1] = make_float4(o[4].y, o[5].y, o[6].y, o[7].y);
    }
}

extern "C" void kernel_launch(void* const* d_in, const int* in_sizes, int n_in,
                              void* d_out, int out_size, void* d_ws, size_t ws_size,
                              hipStream_t stream) {
    const float* x    = (const float*)d_in[0];
    const float* w    = (const float*)d_in[1];
    const float* fc_w = (const float*)d_in[2];
    const float* fc_b = (const float*)d_in[3];
    float* out = (float*)d_out;

    const int Btot = in_sizes[0] / N_QUBITS;   // 262144
    const int grid = (Btot + 511) / 512;       // 2 batches per thread
    hipLaunchKernelGGL(vqc_kernel, dim3(grid), dim3(256), 0, stream,
                       x, w, fc_w, fc_b, out, Btot);
}